// Round 5
// baseline (296.187 us; speedup 1.0000x reference)
//
#include <hip/hip_runtime.h>
#include <cstdint>
#include <cmath>

typedef _Float16 half8 __attribute__((ext_vector_type(8)));
typedef __fp16 fp16x2 __attribute__((ext_vector_type(2)));
typedef unsigned short ushort8 __attribute__((ext_vector_type(8)));
typedef float floatx4 __attribute__((ext_vector_type(4)));

#define VT_STRIDE 2080  // 2048 + 32: breaks 4KB L2 set aliasing on V^T rows

__device__ __forceinline__ unsigned short f2h(float f) {
    union { _Float16 h; unsigned short u; } cv;
    cv.h = (_Float16)f;
    return cv.u;
}

// async global->LDS, 16B per lane; LDS dest is wave-uniform base + lane*16
__device__ __forceinline__ void gll16(const unsigned short* g, unsigned short* l) {
    __builtin_amdgcn_global_load_lds(
        (const __attribute__((address_space(1))) void*)g,
        (__attribute__((address_space(3))) void*)l, 16, 0, 0);
}

// ---------------- cast x fp32 -> fp16 ----------------
__global__ void cast_x_kernel(const float* __restrict__ x, unsigned short* __restrict__ xh, int n8) {
    int idx = blockIdx.x * blockDim.x + threadIdx.x;
    if (idx >= n8) return;
    const float4* p = (const float4*)x;
    float4 a = p[idx * 2], b = p[idx * 2 + 1];
    ushort8 o;
    o[0] = f2h(a.x); o[1] = f2h(a.y); o[2] = f2h(a.z); o[3] = f2h(a.w);
    o[4] = f2h(b.x); o[5] = f2h(b.y); o[6] = f2h(b.z); o[7] = f2h(b.w);
    *(ushort8*)(xh + (size_t)idx * 8) = o;
}

// ---------------- fused transpose+cast of Wq, Wkv, Wout ----------------
__global__ void transpose_fused_kernel(const float* __restrict__ Wq, const float* __restrict__ Wkv,
                                       const float* __restrict__ Wout,
                                       unsigned short* __restrict__ Wqkvt, unsigned short* __restrict__ Wot) {
    __shared__ float tile[32][33];
    int bxi = blockIdx.x;
    const float* in; unsigned short* out; int C; int cb;
    if (bxi < 32)      { in = Wq;   out = Wqkvt;                 C = 1024; cb = bxi; }
    else if (bxi < 36) { in = Wkv;  out = Wqkvt + 1024 * 1024;   C = 128;  cb = bxi - 32; }
    else               { in = Wout; out = Wot;                   C = 1024; cb = bxi - 36; }
    int bx = cb * 32, by = blockIdx.y * 32;
    int x = threadIdx.x, y0 = threadIdx.y;
    #pragma unroll
    for (int k = 0; k < 4; k++) {
        int y = y0 + k * 8;
        tile[y][x] = in[(size_t)(by + y) * C + bx + x];
    }
    __syncthreads();
    #pragma unroll
    for (int k = 0; k < 4; k++) {
        int y = y0 + k * 8;
        out[(size_t)(bx + y) * 1024 + by + x] = f2h(tile[x][y]);
    }
}

// ---------------- GEMM 64M x 128N x 32K, global_load_lds staging, swizzled LDS ----------------
// LDS granule layout: slot(row, g) = row*4 + (g ^ ((row>>1)&3))  -> frag b128 reads 2-way only
// MODE 0: fused q/k/v epilogue; MODE 2: fp32 out + bias
template<int MODE>
__global__ __launch_bounds__(256) void gemm_kernel(
    const unsigned short* __restrict__ A, const unsigned short* __restrict__ Bt,
    unsigned short* __restrict__ oq, unsigned short* __restrict__ ok,
    unsigned short* __restrict__ ov, float* __restrict__ of,
    const float* __restrict__ bias)
{
    __shared__ __align__(16) unsigned short As[64 * 32];
    __shared__ __align__(16) unsigned short Bs[128 * 32];
    const int K = 1024;
    int t = threadIdx.x;
    int w = t >> 6, lane = t & 63, g = lane >> 4, il = lane & 15;
    int wm = w >> 1, wn = w & 1;
    int m0 = blockIdx.y * 64, n0 = blockIdx.x * 128;
    // staging: lane's global source for its fixed LDS slot (swizzled granule col)
    int sg = ((lane & 3) ^ ((lane >> 3) & 3)) * 8;
    const unsigned short* Ag  = A  + (size_t)(m0 + w * 16 + (lane >> 2)) * K + sg;
    const unsigned short* Bg0 = Bt + (size_t)(n0 + w * 32 + (lane >> 2)) * K + sg;
    const unsigned short* Bg1 = Bg0 + (size_t)16 * K;
    unsigned short* Al  = &As[w * 512];
    unsigned short* Bl0 = &Bs[w * 1024];
    unsigned short* Bl1 = &Bs[w * 1024 + 512];
    int gx = (g ^ ((il >> 1) & 3)) * 8;  // swizzled granule offset for frag reads
    floatx4 acc[2][4] = {};
    for (int k0 = 0; k0 < K; k0 += 32) {
        gll16(Ag + k0, Al);
        gll16(Bg0 + k0, Bl0);
        gll16(Bg1 + k0, Bl1);
        __syncthreads();  // drains vmcnt -> staged data visible
        half8 af[2], bf[4];
        #pragma unroll
        for (int mt = 0; mt < 2; mt++) af[mt] = *(const half8*)&As[(wm * 32 + mt * 16 + il) * 32 + gx];
        #pragma unroll
        for (int nt = 0; nt < 4; nt++) bf[nt] = *(const half8*)&Bs[(wn * 64 + nt * 16 + il) * 32 + gx];
        __syncthreads();  // all reads done before next iter's DMA overwrites
        #pragma unroll
        for (int mt = 0; mt < 2; mt++)
            #pragma unroll
            for (int nt = 0; nt < 4; nt++)
                acc[mt][nt] = __builtin_amdgcn_mfma_f32_16x16x32_f16(af[mt], bf[nt], acc[mt][nt], 0, 0, 0);
    }
    #pragma unroll
    for (int mt = 0; mt < 2; mt++) {
        #pragma unroll
        for (int nt = 0; nt < 4; nt++) {
            #pragma unroll
            for (int r = 0; r < 4; r++) {
                int row = m0 + wm * 32 + mt * 16 + 4 * g + r;   // b*2048 + i
                int col = n0 + wn * 64 + nt * 16 + il;
                float v = acc[mt][nt][r];
                if (MODE == 0) {
                    if (col < 1024) {
                        int b = row >> 11, i = row & 2047, h = col >> 6, d = col & 63;
                        // pre-scale into exp2 domain: 0.125 * log2(e)
                        oq[(size_t)((b * 16 + h) * 2048 + i) * 64 + d] = f2h(v * 0.18033688011112042f);
                    } else if (col < 1088) {
                        ok[(size_t)row * 64 + (col - 1024)] = f2h(v);
                    } else {
                        int b = row >> 11, j = row & 2047;
                        ov[(size_t)((b << 6) + (col - 1088)) * VT_STRIDE + j] = f2h(v);
                    }
                } else {
                    of[(size_t)row * 1024 + col] = v + bias[col];
                }
            }
        }
    }
}

// ---------------- flash attention ----------------
// Grid: (32 i-tiles, longest first, 32 b*h) = 1024 blocks -> 4 blocks/CU for latency hiding.
// Block 256 = 4 waves; wave w owns 16 Q rows. S^T = K.Q^T; V from padded global V^T.
__global__ __launch_bounds__(256) void attn_kernel(
    const unsigned short* __restrict__ qh, const unsigned short* __restrict__ kh,
    const unsigned short* __restrict__ vt, const float* __restrict__ rel_emb,
    unsigned short* __restrict__ ob)
{
    __shared__ float bias_tab[256];
    __shared__ __align__(16) unsigned short Pl[64 * 72];  // wave-private P rows, stride 72
    int bx = 31 - blockIdx.x;  // longest blocks dispatch first
    int bh = blockIdx.y;
    int b = bh >> 4, h = bh & 15;
    int t = threadIdx.x;
    int w = t >> 6, lane = t & 63, g = lane >> 4, il = lane & 15;

    // bias table for delta < 256 (bucket saturates at 31 for delta >= 113)
    {
        int dlt = t;
        int bucket;
        if (dlt < 16) bucket = dlt;
        else {
            float lg = logf((float)dlt * 0.0625f) / 2.0794415416798357f;
            int vv = 16 + (int)(lg * 16.0f);
            bucket = vv < 31 ? vv : 31;
        }
        bias_tab[dlt] = rel_emb[bucket * 16 + h] * 11.541560327111708f;
    }
    float cb31 = rel_emb[31 * 16 + h] * 11.541560327111708f;
    __syncthreads();

    const unsigned short* kbase = kh + (size_t)b * (2048 * 64);
    const unsigned short* vbase = vt + (size_t)b * (64 * VT_STRIDE);
    int prow = (w * 16 + il) * 72;

    int iw = bx * 64 + w * 16;
    int i_glob = iw + il;
    const unsigned short* qrow = qh + (size_t)(bh * 2048 + i_glob) * 64;
    half8 qf0 = *(const half8*)(qrow + g * 8);
    half8 qf1 = *(const half8*)(qrow + 32 + g * 8);
    floatx4 O[4] = {};
    float m_run = -1e30f, l_run = 0.0f;

    // prefetch K chunk 0
    half8 kA0[4], kA1[4];
    #pragma unroll
    for (int jt = 0; jt < 4; jt++) {
        const unsigned short* kr = kbase + (size_t)(jt * 16 + il) * 64;
        kA0[jt] = *(const half8*)(kr + g * 8);
        kA1[jt] = *(const half8*)(kr + 32 + g * 8);
    }

    for (int c = 0; c <= bx; c++) {
        int j0 = c * 64;
        // V loads for this chunk issued early (consumed after softmax)
        half8 vf[8];
        #pragma unroll
        for (int ks = 0; ks < 2; ks++)
            #pragma unroll
            for (int dt = 0; dt < 4; dt++)
                vf[ks * 4 + dt] = *(const half8*)(vbase + (size_t)(dt * 16 + il) * VT_STRIDE + j0 + ks * 32 + g * 8);
        // S^T from prefetched K
        floatx4 S[4] = {};
        #pragma unroll
        for (int jt = 0; jt < 4; jt++) {
            S[jt] = __builtin_amdgcn_mfma_f32_16x16x32_f16(kA0[jt], qf0, S[jt], 0, 0, 0);
            S[jt] = __builtin_amdgcn_mfma_f32_16x16x32_f16(kA1[jt], qf1, S[jt], 0, 0, 0);
        }
        // prefetch K for chunk c+1
        half8 kB0[4], kB1[4];
        if (c < bx) {
            #pragma unroll
            for (int jt = 0; jt < 4; jt++) {
                const unsigned short* kr = kbase + (size_t)(j0 + 64 + jt * 16 + il) * 64;
                kB0[jt] = *(const half8*)(kr + g * 8);
                kB1[jt] = *(const half8*)(kr + 32 + g * 8);
            }
        }
        // bias handling: far chunks fold constant bias into the max (no per-element add)
        float s[16], boff;
        if (c + 3 <= bx) {
            #pragma unroll
            for (int q2 = 0; q2 < 16; q2++) s[q2] = S[q2 >> 2][q2 & 3];
            boff = cb31;
        } else if (c < bx) {
            boff = 0.0f;
            #pragma unroll
            for (int jt = 0; jt < 4; jt++)
                #pragma unroll
                for (int r = 0; r < 4; r++)
                    s[jt * 4 + r] = S[jt][r] + bias_tab[i_glob - (j0 + jt * 16 + 4 * g + r)];
        } else {
            boff = 0.0f;
            #pragma unroll
            for (int jt = 0; jt < 4; jt++) {
                #pragma unroll
                for (int r = 0; r < 4; r++) {
                    int delta = i_glob - (j0 + jt * 16 + 4 * g + r);
                    int di = delta > 0 ? delta : 0;
                    s[jt * 4 + r] = (delta >= 0) ? (S[jt][r] + bias_tab[di]) : -1e30f;
                }
            }
        }
        // online softmax (exp2 domain); rows per (lane&15), reduce over 4 g-groups
        float mx = s[0];
        #pragma unroll
        for (int q2 = 1; q2 < 16; q2++) mx = fmaxf(mx, s[q2]);
        mx = fmaxf(mx, __shfl_xor(mx, 16));
        mx = fmaxf(mx, __shfl_xor(mx, 32));
        float m_new = fmaxf(m_run, mx + boff);
        float mc = m_new - boff;
        float alpha = __builtin_amdgcn_exp2f(m_run - m_new);
        float p[16], psum = 0.0f;
        #pragma unroll
        for (int q2 = 0; q2 < 16; q2++) { p[q2] = __builtin_amdgcn_exp2f(s[q2] - mc); psum += p[q2]; }
        psum += __shfl_xor(psum, 16);
        psum += __shfl_xor(psum, 32);
        l_run = l_run * alpha + psum;
        m_run = m_new;
        float arow[4];
        #pragma unroll
        for (int r = 0; r < 4; r++) arow[r] = __shfl(alpha, 4 * g + r);
        #pragma unroll
        for (int dt = 0; dt < 4; dt++)
            #pragma unroll
            for (int r = 0; r < 4; r++) O[dt][r] *= arow[r];
        // pack P fp16 -> wave-private LDS (C-layout -> A-layout transform)
        #pragma unroll
        for (int jt = 0; jt < 4; jt++) {
            union { fp16x2 h; unsigned int u; } c0, c1;
            c0.h = __builtin_amdgcn_cvt_pkrtz(p[jt * 4 + 0], p[jt * 4 + 1]);
            c1.h = __builtin_amdgcn_cvt_pkrtz(p[jt * 4 + 2], p[jt * 4 + 3]);
            uint2 u; u.x = c0.u; u.y = c1.u;
            *(uint2*)&Pl[prow + jt * 16 + 4 * g] = u;
        }
        // PV with prefetched V
        #pragma unroll
        for (int ks = 0; ks < 2; ks++) {
            half8 pf = *(const half8*)&Pl[prow + ks * 32 + g * 8];
            #pragma unroll
            for (int dt = 0; dt < 4; dt++)
                O[dt] = __builtin_amdgcn_mfma_f32_16x16x32_f16(pf, vf[ks * 4 + dt], O[dt], 0, 0, 0);
        }
        // rotate prefetched K
        if (c < bx) {
            #pragma unroll
            for (int jt = 0; jt < 4; jt++) { kA0[jt] = kB0[jt]; kA1[jt] = kB1[jt]; }
        }
    }
    // epilogue: normalize, store [b*2048+i][h*64+d] fp16
    float inv[4];
    #pragma unroll
    for (int r = 0; r < 4; r++) inv[r] = 1.0f / __shfl(l_run, 4 * g + r);
    #pragma unroll
    for (int dt = 0; dt < 4; dt++) {
        #pragma unroll
        for (int r = 0; r < 4; r++) {
            int i = iw + 4 * g + r;
            int d = dt * 16 + il;
            ob[(size_t)(b * 2048 + i) * 1024 + h * 64 + d] = f2h(O[dt][r] * inv[r]);
        }
    }
}

extern "C" void kernel_launch(void* const* d_in, const int* in_sizes, int n_in,
                              void* d_out, int out_size, void* d_ws, size_t ws_size,
                              hipStream_t stream) {
    const float* x    = (const float*)d_in[0];
    const float* Wq   = (const float*)d_in[1];
    const float* Wkv  = (const float*)d_in[2];
    const float* Wout = (const float*)d_in[3];
    const float* bout = (const float*)d_in[4];
    const float* rel  = (const float*)d_in[5];
    float* out = (float*)d_out;

    unsigned short* ws    = (unsigned short*)d_ws;
    unsigned short* xh    = ws;                      // [4096][1024] fp16 x; reused as attn out
    unsigned short* qh    = xh + 4194304;            // [b,h,i,d] fp16, exp2-domain prescaled
    unsigned short* kh    = qh + 4194304;            // [b*2048+j][64]
    unsigned short* vt    = kh + 262144;             // [b][64][VT_STRIDE] padded V^T
    unsigned short* Wqkvt = vt + 2 * 64 * VT_STRIDE; // [1152][1024]
    unsigned short* Wot   = Wqkvt + 1179648;         // [1024][1024]
    unsigned short* ob    = xh;

    cast_x_kernel<<<2048, 256, 0, stream>>>(x, xh, 524288);
    transpose_fused_kernel<<<dim3(68, 32), dim3(32, 8), 0, stream>>>(Wq, Wkv, Wout, Wqkvt, Wot);
    gemm_kernel<0><<<dim3(9, 64), 256, 0, stream>>>(xh, Wqkvt, qh, kh, vt, nullptr, nullptr);
    attn_kernel<<<dim3(32, 32), 256, 0, stream>>>(qh, kh, vt, rel, ob);
    gemm_kernel<2><<<dim3(8, 64), 256, 0, stream>>>(ob, Wot, nullptr, nullptr, nullptr, out, bout);
}

// Round 7
// 242.789 us; speedup vs baseline: 1.2199x; 1.2199x over previous
//
#include <hip/hip_runtime.h>
#include <cstdint>
#include <cmath>

typedef _Float16 half8 __attribute__((ext_vector_type(8)));
typedef _Float16 half4 __attribute__((ext_vector_type(4)));
typedef __fp16 fp16x2 __attribute__((ext_vector_type(2)));
typedef unsigned short ushort8 __attribute__((ext_vector_type(8)));
typedef unsigned short ushort4v __attribute__((ext_vector_type(4)));
typedef float floatx4 __attribute__((ext_vector_type(4)));

#define VT_STRIDE 2080  // 2048 + 32: breaks 4KB L2 set aliasing on V^T rows

__device__ __forceinline__ unsigned short f2h(float f) {
    union { _Float16 h; unsigned short u; } cv;
    cv.h = (_Float16)f;
    return cv.u;
}

// async global->LDS, 16B per lane; LDS dest is wave-uniform base + lane*16
__device__ __forceinline__ void gll16(const unsigned short* g, unsigned short* l) {
    __builtin_amdgcn_global_load_lds(
        (const __attribute__((address_space(1))) void*)g,
        (__attribute__((address_space(3))) void*)l, 16, 0, 0);
}

// ---------------- cast x fp32 -> fp16 ----------------
__global__ void cast_x_kernel(const float* __restrict__ x, unsigned short* __restrict__ xh, int n8) {
    int idx = blockIdx.x * blockDim.x + threadIdx.x;
    if (idx >= n8) return;
    const float4* p = (const float4*)x;
    float4 a = p[idx * 2], b = p[idx * 2 + 1];
    ushort8 o;
    o[0] = f2h(a.x); o[1] = f2h(a.y); o[2] = f2h(a.z); o[3] = f2h(a.w);
    o[4] = f2h(b.x); o[5] = f2h(b.y); o[6] = f2h(b.z); o[7] = f2h(b.w);
    *(ushort8*)(xh + (size_t)idx * 8) = o;
}

// ---------------- fused transpose+cast of Wq, Wkv, Wout ----------------
__global__ void transpose_fused_kernel(const float* __restrict__ Wq, const float* __restrict__ Wkv,
                                       const float* __restrict__ Wout,
                                       unsigned short* __restrict__ Wqkvt, unsigned short* __restrict__ Wot) {
    __shared__ float tile[32][33];
    int bxi = blockIdx.x;
    const float* in; unsigned short* out; int C; int cb;
    if (bxi < 32)      { in = Wq;   out = Wqkvt;                 C = 1024; cb = bxi; }
    else if (bxi < 36) { in = Wkv;  out = Wqkvt + 1024 * 1024;   C = 128;  cb = bxi - 32; }
    else               { in = Wout; out = Wot;                   C = 1024; cb = bxi - 36; }
    int bx = cb * 32, by = blockIdx.y * 32;
    int x = threadIdx.x, y0 = threadIdx.y;
    #pragma unroll
    for (int k = 0; k < 4; k++) {
        int y = y0 + k * 8;
        tile[y][x] = in[(size_t)(by + y) * C + bx + x];
    }
    __syncthreads();
    #pragma unroll
    for (int k = 0; k < 4; k++) {
        int y = y0 + k * 8;
        out[(size_t)(bx + y) * 1024 + by + x] = f2h(tile[x][y]);
    }
}

// ---------------- GEMM 64M x 128N x 64K, global_load_lds staging, swizzled LDS ----------------
// LDS: row = 8 granules of 16B; slot(row, gk) = row*8 + (gk ^ (row&7)); frag b128 reads 2-way only.
// MODE 0: fused q/k/v epilogue; MODE 2: fp32 out + bias
template<int MODE>
__global__ __launch_bounds__(256) void gemm_kernel(
    const unsigned short* __restrict__ A, const unsigned short* __restrict__ Bt,
    unsigned short* __restrict__ oq, unsigned short* __restrict__ ok,
    unsigned short* __restrict__ ov, float* __restrict__ of,
    const float* __restrict__ bias)
{
    __shared__ __align__(16) unsigned short As[64 * 64];
    __shared__ __align__(16) unsigned short Bs[128 * 64];
    const int K = 1024;
    int t = threadIdx.x;
    int w = t >> 6, lane = t & 63, g = lane >> 4, il = lane & 15;
    int wm = w >> 1, wn = w & 1;
    int m0 = blockIdx.y * 64, n0 = blockIdx.x * 128;
    int sr8 = lane >> 3;
    int sg8 = ((lane & 7) ^ sr8) * 8;   // swizzled granule offset for staging source
    const unsigned short* Ag = A  + (size_t)(m0 + w * 16 + sr8) * K + sg8;
    const unsigned short* Bg = Bt + (size_t)(n0 + w * 32 + sr8) * K + sg8;
    unsigned short* Al = &As[(w * 16) * 64];
    unsigned short* Bl = &Bs[(w * 32) * 64];
    floatx4 acc[2][4] = {};
    for (int k0 = 0; k0 < K; k0 += 64) {
        gll16(Ag + k0, Al);
        gll16(Ag + (size_t)8 * K + k0, Al + 8 * 64);
        gll16(Bg + k0, Bl);
        gll16(Bg + (size_t)8 * K + k0, Bl + 8 * 64);
        gll16(Bg + (size_t)16 * K + k0, Bl + 16 * 64);
        gll16(Bg + (size_t)24 * K + k0, Bl + 24 * 64);
        __syncthreads();  // drains vmcnt -> staged data visible
        half8 af[2][2], bf[4][2];
        #pragma unroll
        for (int mt = 0; mt < 2; mt++) {
            int row = wm * 32 + mt * 16 + il;
            #pragma unroll
            for (int khi = 0; khi < 2; khi++)
                af[mt][khi] = *(const half8*)&As[row * 64 + (((khi * 4 + g) ^ (row & 7)) * 8)];
        }
        #pragma unroll
        for (int nt = 0; nt < 4; nt++) {
            int row = wn * 64 + nt * 16 + il;
            #pragma unroll
            for (int khi = 0; khi < 2; khi++)
                bf[nt][khi] = *(const half8*)&Bs[row * 64 + (((khi * 4 + g) ^ (row & 7)) * 8)];
        }
        __syncthreads();  // all reads done before next iter's DMA overwrites
        #pragma unroll
        for (int mt = 0; mt < 2; mt++)
            #pragma unroll
            for (int nt = 0; nt < 4; nt++) {
                acc[mt][nt] = __builtin_amdgcn_mfma_f32_16x16x32_f16(af[mt][0], bf[nt][0], acc[mt][nt], 0, 0, 0);
                acc[mt][nt] = __builtin_amdgcn_mfma_f32_16x16x32_f16(af[mt][1], bf[nt][1], acc[mt][nt], 0, 0, 0);
            }
    }
    #pragma unroll
    for (int mt = 0; mt < 2; mt++) {
        #pragma unroll
        for (int nt = 0; nt < 4; nt++) {
            #pragma unroll
            for (int r = 0; r < 4; r++) {
                int row = m0 + wm * 32 + mt * 16 + 4 * g + r;   // b*2048 + i
                int col = n0 + wn * 64 + nt * 16 + il;
                float v = acc[mt][nt][r];
                if (MODE == 0) {
                    if (col < 1024) {
                        int b = row >> 11, i = row & 2047, h = col >> 6, d = col & 63;
                        // pre-scale into exp2 domain: 0.125 * log2(e)
                        oq[(size_t)((b * 16 + h) * 2048 + i) * 64 + d] = f2h(v * 0.18033688011112042f);
                    } else if (col < 1088) {
                        ok[(size_t)row * 64 + (col - 1024)] = f2h(v);
                    } else {
                        int b = row >> 11, j = row & 2047;
                        ov[(size_t)((b << 6) + (col - 1088)) * VT_STRIDE + j] = f2h(v);
                    }
                } else {
                    of[(size_t)row * 1024 + col] = v + bias[col];
                }
            }
        }
    }
}

// ---------------- flash attention: paired 32-row tiles, in-block j-split (flash-decode) ----------------
// Grid (32 pairs, 32 bh), block 256 = 4 waves. Tile = 32 rows; waves {rg, split}:
// rg = w&1 picks 16 rows; split = w>>1 processes even/odd 64-j chunks. Partials merged via LDS.
// S^T = K.Q^T (x32 MFMA); PV uses 16x16x16 MFMA with P direct from registers (no LDS roundtrip).
__global__ __launch_bounds__(256, 4) void attn_kernel(
    const unsigned short* __restrict__ qh, const unsigned short* __restrict__ kh,
    const unsigned short* __restrict__ vt, const float* __restrict__ rel_emb,
    unsigned short* __restrict__ ob)
{
    __shared__ float bias_tab[256];
    __shared__ float Obuf[32][65];
    __shared__ float mbuf[32], lbuf[32];
    int pr = blockIdx.x;
    int bh = blockIdx.y;
    int b = bh >> 4, h = bh & 15;
    int t = threadIdx.x;
    int w = t >> 6, lane = t & 63, g = lane >> 4, il = lane & 15;
    int rg = w & 1, sp = w >> 1;

    // bias table for delta in [0,256) (bucket saturates at 31 for delta >= 113)
    {
        int dlt = t;  // 256 threads -> one entry each
        int bucket;
        if (dlt < 16) bucket = dlt;
        else {
            float lg = logf((float)dlt * 0.0625f) / 2.0794415416798357f;
            int vv = 16 + (int)(lg * 16.0f);
            bucket = vv < 31 ? vv : 31;
        }
        bias_tab[dlt] = rel_emb[bucket * 16 + h] * 11.541560327111708f;
    }
    float cb31 = rel_emb[31 * 16 + h] * 11.541560327111708f;
    __syncthreads();

    const unsigned short* kbase = kh + (size_t)b * (2048 * 64);
    const unsigned short* vbase = vt + (size_t)b * (64 * VT_STRIDE);

    for (int tt = 0; tt < 2; tt++) {
        int ti = tt ? pr : 63 - pr;      // paired tiles: total chunk work constant
        int iw = ti * 32 + rg * 16;
        int i_glob = iw + il;
        const unsigned short* qrow = qh + (size_t)(bh * 2048 + i_glob) * 64;
        half8 qf0 = *(const half8*)(qrow + g * 8);
        half8 qf1 = *(const half8*)(qrow + 32 + g * 8);
        floatx4 O[4] = {};
        float m_run = -1e30f, l_run = 0.0f;
        int c_last = ti >> 1;

        for (int c = sp; c <= c_last; c += 2) {
            int j0 = c * 64;
            // K frags (x32 A-layout: rows j, k over d)
            half8 k0[4], k1[4];
            #pragma unroll
            for (int jt = 0; jt < 4; jt++) {
                const unsigned short* kr = kbase + (size_t)(j0 + jt * 16 + il) * 64;
                k0[jt] = *(const half8*)(kr + g * 8);
                k1[jt] = *(const half8*)(kr + 32 + g * 8);
            }
            // V frags for PV (x16 B-layout: k=4g+u over j, n=d=dt*16+il) -- b64 from padded V^T
            half4 vfr[16];
            #pragma unroll
            for (int jt = 0; jt < 4; jt++)
                #pragma unroll
                for (int dt = 0; dt < 4; dt++) {
                    union { ushort4v u4; half4 h4; } vv;
                    vv.u4 = *(const ushort4v*)(vbase + (size_t)(dt * 16 + il) * VT_STRIDE + j0 + jt * 16 + 4 * g);
                    vfr[jt * 4 + dt] = vv.h4;
                }
            // S^T
            floatx4 S[4] = {};
            #pragma unroll
            for (int jt = 0; jt < 4; jt++) {
                S[jt] = __builtin_amdgcn_mfma_f32_16x16x32_f16(k0[jt], qf0, S[jt], 0, 0, 0);
                S[jt] = __builtin_amdgcn_mfma_f32_16x16x32_f16(k1[jt], qf1, S[jt], 0, 0, 0);
            }
            // bias: far = fold constant into max; mid = table; near-diag = table + mask
            float s[16], boff;
            if (j0 + 176 <= iw) {
                boff = cb31;
                #pragma unroll
                for (int q2 = 0; q2 < 16; q2++) s[q2] = S[q2 >> 2][q2 & 3];
            } else if (j0 + 64 <= iw) {
                boff = 0.0f;
                #pragma unroll
                for (int jt = 0; jt < 4; jt++)
                    #pragma unroll
                    for (int r = 0; r < 4; r++)
                        s[jt * 4 + r] = S[jt][r] + bias_tab[i_glob - (j0 + jt * 16 + 4 * g + r)];
            } else {
                boff = 0.0f;
                #pragma unroll
                for (int jt = 0; jt < 4; jt++) {
                    #pragma unroll
                    for (int r = 0; r < 4; r++) {
                        int delta = i_glob - (j0 + jt * 16 + 4 * g + r);
                        int di = delta > 0 ? delta : 0;
                        s[jt * 4 + r] = (delta >= 0) ? (S[jt][r] + bias_tab[di]) : -1e30f;
                    }
                }
            }
            // online softmax (exp2 domain); rows per (lane&15), reduce over 4 g-groups
            float mx = s[0];
            #pragma unroll
            for (int q2 = 1; q2 < 16; q2++) mx = fmaxf(mx, s[q2]);
            mx = fmaxf(mx, __shfl_xor(mx, 16));
            mx = fmaxf(mx, __shfl_xor(mx, 32));
            float m_new = fmaxf(m_run, mx + boff);
            float mc = m_new - boff;
            float alpha = __builtin_amdgcn_exp2f(m_run - m_new);
            float p[16], psum = 0.0f;
            #pragma unroll
            for (int q2 = 0; q2 < 16; q2++) { p[q2] = __builtin_amdgcn_exp2f(s[q2] - mc); psum += p[q2]; }
            psum += __shfl_xor(psum, 16);
            psum += __shfl_xor(psum, 32);
            l_run = l_run * alpha + psum;
            m_run = m_new;
            if (__ballot(alpha < 1.0f)) {  // skip rescale when max unchanged everywhere
                float arow[4];
                #pragma unroll
                for (int r = 0; r < 4; r++) arow[r] = __shfl(alpha, 4 * g + r);
                #pragma unroll
                for (int dt = 0; dt < 4; dt++)
                    #pragma unroll
                    for (int r = 0; r < 4; r++) O[dt][r] *= arow[r];
            }
            // PV: A = P direct from registers (x16 A-layout == S C-layout), B = V frags
            #pragma unroll
            for (int jt = 0; jt < 4; jt++) {
                union { fp16x2 h2[2]; half4 h4; } pk;
                pk.h2[0] = __builtin_amdgcn_cvt_pkrtz(p[jt * 4 + 0], p[jt * 4 + 1]);
                pk.h2[1] = __builtin_amdgcn_cvt_pkrtz(p[jt * 4 + 2], p[jt * 4 + 3]);
                #pragma unroll
                for (int dt = 0; dt < 4; dt++)
                    O[dt] = __builtin_amdgcn_mfma_f32_16x16x16f16(pk.h4, vfr[jt * 4 + dt], O[dt], 0, 0, 0);
            }
        }
        // merge the two j-splits via LDS
        if (sp == 1) {
            #pragma unroll
            for (int dt = 0; dt < 4; dt++)
                #pragma unroll
                for (int r = 0; r < 4; r++)
                    Obuf[rg * 16 + 4 * g + r][dt * 16 + il] = O[dt][r];
            if (g == 0) { mbuf[rg * 16 + il] = m_run; lbuf[rg * 16 + il] = l_run; }
        }
        __syncthreads();
        if (sp == 0) {
            #pragma unroll
            for (int r = 0; r < 4; r++) {
                int row = rg * 16 + 4 * g + r;
                float m1 = mbuf[row], l1 = lbuf[row];
                float m0r = __shfl(m_run, 4 * g + r);
                float l0r = __shfl(l_run, 4 * g + r);
                float mM = fmaxf(m0r, m1);
                float a0 = __builtin_amdgcn_exp2f(m0r - mM);
                float a1 = __builtin_amdgcn_exp2f(m1 - mM);
                float inv = 1.0f / (l0r * a0 + l1 * a1);
                #pragma unroll
                for (int dt = 0; dt < 4; dt++) {
                    float v = (O[dt][r] * a0 + Obuf[row][dt * 16 + il] * a1) * inv;
                    ob[(size_t)(b * 2048 + ti * 32 + row) * 1024 + h * 64 + dt * 16 + il] = f2h(v);
                }
            }
        }
        __syncthreads();  // protect Obuf/mbuf/lbuf before next tile
    }
}

extern "C" void kernel_launch(void* const* d_in, const int* in_sizes, int n_in,
                              void* d_out, int out_size, void* d_ws, size_t ws_size,
                              hipStream_t stream) {
    const float* x    = (const float*)d_in[0];
    const float* Wq   = (const float*)d_in[1];
    const float* Wkv  = (const float*)d_in[2];
    const float* Wout = (const float*)d_in[3];
    const float* bout = (const float*)d_in[4];
    const float* rel  = (const float*)d_in[5];
    float* out = (float*)d_out;

    unsigned short* ws    = (unsigned short*)d_ws;
    unsigned short* xh    = ws;                      // [4096][1024] fp16 x; reused as attn out
    unsigned short* qh    = xh + 4194304;            // [b,h,i,d] fp16, exp2-domain prescaled
    unsigned short* kh    = qh + 4194304;            // [b*2048+j][64]
    unsigned short* vt    = kh + 262144;             // [b][64][VT_STRIDE] padded V^T
    unsigned short* Wqkvt = vt + 2 * 64 * VT_STRIDE; // [1152][1024]
    unsigned short* Wot   = Wqkvt + 1179648;         // [1024][1024]
    unsigned short* ob    = xh;

    cast_x_kernel<<<2048, 256, 0, stream>>>(x, xh, 524288);
    transpose_fused_kernel<<<dim3(68, 32), dim3(32, 8), 0, stream>>>(Wq, Wkv, Wout, Wqkvt, Wot);
    gemm_kernel<0><<<dim3(9, 64), 256, 0, stream>>>(xh, Wqkvt, qh, kh, vt, nullptr, nullptr);
    attn_kernel<<<dim3(32, 32), 256, 0, stream>>>(qh, kh, vt, rel, ob);
    gemm_kernel<2><<<dim3(8, 64), 256, 0, stream>>>(ob, Wot, nullptr, nullptr, nullptr, out, bout);
}